// Round 4
// baseline (110.431 us; speedup 1.0000x reference)
//
#include <hip/hip_runtime.h>

// NCC forward: X,Y (16,32,64,24) fp32, PS=5, D=2, EPS=0.01
// out[b, c*120 + yo*24 + i, h, x] =
//   (sum_{dy,dx} (Xp[h+dy,x+dx]-Em[h,x]) * Yp[h+yo+dy,i+dx])
//   / (25*Es[h,x] * Fs[h+yo,i])
// Xp = X padded by 2 (H,W); Yp = Y padded by 4 (H), 2 (W).
// One block per (b,c); thread = (x, i) in 24x24; sliding G-row decomposition:
//   G(r,yo) = sum_dx Xp[r,x+dx]*Yp[r+yo,i+dx];  cross(h,yo)=sum_{dy} G(h+dy,yo)
// with register rolling buffers for 5 Y rows + 5 staggered accumulators.

#define NT 576   // 24*24 threads = 9 waves

__global__ __launch_bounds__(NT)
void ncc_kernel(const float* __restrict__ X, const float* __restrict__ Y,
                float* __restrict__ out)
{
    __shared__ float sXp[70*28];   // padded X rows 0..67 (+2 zero overrun rows)
    __shared__ float sYp[74*28];   // padded Y rows 0..71 (+2 zero overrun rows)
    __shared__ float sEm[64*24];   // patch mean of X at (h,x)
    __shared__ float sIE[64*24];   // 1/(25*Es)
    __shared__ float sSF[70*24];   // sum of Y patch at (h',i)  (+2 pad rows)
    __shared__ float sIF[70*24];   // 1/Fs                      (+2 pad rows)

    const int tid = threadIdx.x;
    const int blk = blockIdx.x;
    const int b = blk >> 5;        // /32
    const int c = blk & 31;
    const float* Xc = X + (size_t)(b*32 + c) * (64*24);
    const float* Yc = Y + (size_t)(b*32 + c) * (64*24);

    // ---- Phase A: stage padded channels into LDS ----
    for (int idx = tid; idx < 70*28; idx += NT) {
        int r = idx / 28, cc = idx - r*28;
        int hh = r - 2, ww = cc - 2;
        float v = 0.f;
        if (hh >= 0 && hh < 64 && ww >= 0 && ww < 24) v = Xc[hh*24 + ww];
        sXp[idx] = v;
    }
    for (int idx = tid; idx < 74*28; idx += NT) {
        int r = idx / 28, cc = idx - r*28;
        int hh = r - 4, ww = cc - 2;
        float v = 0.f;
        if (hh >= 0 && hh < 64 && ww >= 0 && ww < 24) v = Yc[hh*24 + ww];
        sYp[idx] = v;
    }
    __syncthreads();

    // ---- Phase B: per-position patch statistics ----
    for (int idx = tid; idx < 64*24; idx += NT) {
        int h = idx / 24, xx = idx - h*24;
        float s = 0.f, s2 = 0.f;
        #pragma unroll
        for (int dy = 0; dy < 5; ++dy)
            #pragma unroll
            for (int dx = 0; dx < 5; ++dx) {
                float v = sXp[(h+dy)*28 + xx + dx];
                s += v; s2 = fmaf(v, v, s2);
            }
        float var = (s2 - s*s*0.04f) * (1.f/24.f);
        var = fmaxf(var, 0.f);
        sEm[idx] = s * 0.04f;
        sIE[idx] = 1.f / (25.f * (sqrtf(var) + 0.01f));
    }
    for (int idx = tid; idx < 70*24; idx += NT) {
        int hp = idx / 24, ii = idx - hp*24;
        float s = 0.f, s2 = 0.f;
        if (hp < 68) {
            #pragma unroll
            for (int dy = 0; dy < 5; ++dy)
                #pragma unroll
                for (int dx = 0; dx < 5; ++dx) {
                    float v = sYp[(hp+dy)*28 + ii + dx];
                    s += v; s2 = fmaf(v, v, s2);
                }
        }
        float var = (s2 - s*s*0.04f) * (1.f/24.f);
        var = fmaxf(var, 0.f);
        sSF[idx] = s;
        sIF[idx] = 1.f / (sqrtf(var) + 0.01f);
    }
    __syncthreads();

    // ---- Phase C: sliding-row cross-correlation ----
    const int x = tid % 24;        // X column
    const int i = tid / 24;        // Y column
    const size_t outBase = ((size_t)b*3840 + (size_t)c*120 + i) * 1536 + x;

    // Y row rolling buffer: at start of step r, yr0..yr3 = Yp rows r..r+3 (cols i..i+4)
    float yr0[5], yr1[5], yr2[5], yr3[5];
    #pragma unroll
    for (int d = 0; d < 5; ++d) {
        yr0[d] = sYp[0*28 + i + d];
        yr1[d] = sYp[1*28 + i + d];
        yr2[d] = sYp[2*28 + i + d];
        yr3[d] = sYp[3*28 + i + d];
    }
    // staggered accumulators: acc0 completes (5 G-rows) at current step
    float acc0[5] = {0,0,0,0,0}, acc1[5] = {0,0,0,0,0}, acc2[5] = {0,0,0,0,0},
          acc3[5] = {0,0,0,0,0}, acc4[5] = {0,0,0,0,0};
    // rolling SF / 1/Fs: at start of step r, sf0..sf3 = rows r-4..r-1
    float sf0=0.f, sf1=0.f, sf2=0.f, sf3=0.f;
    float if0=0.f, if1=0.f, if2=0.f, if3=0.f;

    #pragma unroll 5
    for (int r = 0; r < 70; ++r) {
        float xr[5], yn[5];
        #pragma unroll
        for (int d = 0; d < 5; ++d) {
            xr[d] = sXp[r*28 + x + d];       // X row r (this step's G row)
            yn[d] = sYp[(r+4)*28 + i + d];   // new Y row r+4
        }
        float sf4 = sSF[r*24 + i];           // SF row r
        float if4 = sIF[r*24 + i];

        float g[5] = {0,0,0,0,0};            // G(r, yo) for yo=0..4
        #pragma unroll
        for (int d = 0; d < 5; ++d) {
            g[0] = fmaf(xr[d], yr0[d], g[0]);
            g[1] = fmaf(xr[d], yr1[d], g[1]);
            g[2] = fmaf(xr[d], yr2[d], g[2]);
            g[3] = fmaf(xr[d], yr3[d], g[3]);
            g[4] = fmaf(xr[d], yn[d],  g[4]);
        }
        #pragma unroll
        for (int yo = 0; yo < 5; ++yo) {
            acc0[yo] += g[yo]; acc1[yo] += g[yo]; acc2[yo] += g[yo];
            acc3[yo] += g[yo]; acc4[yo] += g[yo];
        }

        if (r >= 4 && r < 68) {              // emit output row h = r-4
            const int h = r - 4;
            const float em = sEm[h*24 + x];
            const float ie = sIE[h*24 + x];
            float* op = out + outBase + (size_t)(h*24);
            op[0     ] = (acc0[0] - em*sf0) * ie * if0;   // yo=0 (SF row h)
            op[36864 ] = (acc0[1] - em*sf1) * ie * if1;   // yo=1
            op[73728 ] = (acc0[2] - em*sf2) * ie * if2;   // yo=2
            op[110592] = (acc0[3] - em*sf3) * ie * if3;   // yo=3
            op[147456] = (acc0[4] - em*sf4) * ie * if4;   // yo=4 (SF row h+4 = r)
        }

        // rotate rolling state (renamed away under unroll)
        #pragma unroll
        for (int yo = 0; yo < 5; ++yo) {
            acc0[yo] = acc1[yo]; acc1[yo] = acc2[yo]; acc2[yo] = acc3[yo];
            acc3[yo] = acc4[yo]; acc4[yo] = 0.f;
        }
        #pragma unroll
        for (int d = 0; d < 5; ++d) {
            yr0[d] = yr1[d]; yr1[d] = yr2[d]; yr2[d] = yr3[d]; yr3[d] = yn[d];
        }
        sf0=sf1; sf1=sf2; sf2=sf3; sf3=sf4;
        if0=if1; if1=if2; if2=if3; if3=if4;
    }
}

extern "C" void kernel_launch(void* const* d_in, const int* in_sizes, int n_in,
                              void* d_out, int out_size, void* d_ws, size_t ws_size,
                              hipStream_t stream) {
    const float* X = (const float*)d_in[0];
    const float* Y = (const float*)d_in[1];
    float* out = (float*)d_out;
    ncc_kernel<<<dim3(16*32), dim3(NT), 0, stream>>>(X, Y, out);
}